// Round 20
// baseline (173.481 us; speedup 1.0000x reference)
//
#include <hip/hip_runtime.h>
#include <stdint.h>

typedef __attribute__((ext_vector_type(8))) short bf16x8;
typedef __attribute__((ext_vector_type(4))) float f32x4;
typedef __attribute__((ext_vector_type(4))) unsigned int u32x4;

#define NSP 65536

// workspace byte offsets
#define WS_XN     0ULL         // 33554432  bf16 xnf fragment-native (kvctx + final)
#define WS_WFRAG  33554432ULL  // 524288    Wkv fragment buffer
#define WS_WEFRAG 34078720ULL  // 131072    Weff fragment buffer
#define WS_PART   34209792ULL  // 2048      stats partials -> reduced sumexp[512]
#define WS_AB     34211840ULL  // 2048      per-channel a,b
#define WS_CTX    34215936ULL  // 131072    ctx[8][64][64]
#define WS_W2     34347008ULL  // 1048576   W2[256][512]
#define WS_WEFF   35395584ULL  // 262144    Weff[256][256]
#define WS_BEFF   35657728ULL  // 1024      beff[256]

// d_out scratch (consumed by k_ctxred before k_final overwrites d_out):
//   ctxp (f32)  [32MB .. 40MB)    512 blocks * 4096 partials
//   sump (f32)  [40MB .. +128KB)  [h*64+d][chunk64]

__device__ __forceinline__ unsigned short f2bf(float f) {
  union { float f; uint32_t u; } v; v.f = f;
  uint32_t r = v.u + 0x7FFFu + ((v.u >> 16) & 1u);
  return (unsigned short)(r >> 16);
}
__device__ __forceinline__ float bf2f(unsigned short b) {
  union { uint32_t u; float f; } v; v.u = ((uint32_t)b) << 16;
  return v.f;
}

// ---------------- GroupNorm stats ----------------
__global__ void k_stats(const float* __restrict__ x, float* __restrict__ part) {
  __shared__ float ss[256], sq[256];
  const int t = threadIdx.x, b = blockIdx.x;
  const f32x4* p = (const f32x4*)(x + (size_t)b * 65536);
  float s = 0.f, qq = 0.f;
  for (int k = 0; k < 64; ++k) {
    f32x4 v = __builtin_nontemporal_load(p + t + 256 * k);
    s  += v[0] + v[1] + v[2] + v[3];
    qq += v[0] * v[0] + v[1] * v[1] + v[2] * v[2] + v[3] * v[3];
  }
  ss[t] = s; sq[t] = qq;
  __syncthreads();
  for (int st = 128; st > 0; st >>= 1) {
    if (t < st) { ss[t] += ss[t + st]; sq[t] += sq[t + st]; }
    __syncthreads();
  }
  if (t == 0) { part[2 * b] = ss[0]; part[2 * b + 1] = sq[0]; }
}

// ---------------- per-channel a,b ----------------
__global__ void k_coef(const float* __restrict__ part, const float* __restrict__ gn_w,
                       const float* __restrict__ gn_b, float* __restrict__ ab) {
  const int c = threadIdx.x;
  const int g = c >> 3;
  float s = 0.f, q = 0.f;
  for (int j = 0; j < 8; ++j) { s += part[(g * 8 + j) * 2]; q += part[(g * 8 + j) * 2 + 1]; }
  const float inv = 1.0f / 524288.0f;
  const float mean = s * inv;
  const float var = q * inv - mean * mean;
  const float rstd = rsqrtf(var + 1e-5f);
  const float a = gn_w[c] * rstd;
  ab[c] = a;
  ab[256 + c] = gn_b[c] - mean * a;
}

// ---------------- normalize + cast -> fragment-native xnf only ----------------
__global__ void k_xn(const float* __restrict__ x, const float* __restrict__ ab,
                     unsigned short* __restrict__ xnf) {
  __shared__ float tile[64][66];
  const int t = threadIdx.x;
  const int nb = blockIdx.x, cb = blockIdx.y;
  {
    const int cl = t >> 2, nc = t & 3;
    const int c = cb * 64 + cl;
    const float a = ab[c], b = ab[256 + c];
    const f32x4* src = (const f32x4*)(x + (size_t)c * NSP + nb * 64 + nc * 16);
#pragma unroll
    for (int j = 0; j < 4; ++j) {
      f32x4 v = __builtin_nontemporal_load(src + j);
      v = v * a + b;
      *(f32x4*)&tile[cl][nc * 16 + j * 4] = v;
    }
  }
  __syncthreads();
  {
    const int l = t & 63, w0 = t >> 6;
    u32x4* xnf4 = (u32x4*)xnf;
#pragma unroll
    for (int u2 = 0; u2 < 2; ++u2) {
      const int fp = w0 + u2 * 4;          // 0..7
      const int fl = fp >> 1, ksl = fp & 1;
      union { unsigned short s[8]; u32x4 v; } pk2;
#pragma unroll
      for (int e = 0; e < 8; ++e)
        pk2.s[e] = f2bf(tile[ksl * 32 + (l >> 4) * 8 + e][fl * 16 + (l & 15)]);
      xnf4[((size_t)(nb * 4 + fl) * 8 + cb * 2 + ksl) * 64 + l] = pk2.v;
    }
  }
}

// ---------------- pre-permute Wkv rows into MFMA B-fragment order ----------------
__global__ void k_wfrag(const float* __restrict__ qkv_w, unsigned short* __restrict__ wf) {
  const int blk = blockIdx.x;                 // blk = ks*64 + cf
  const int l = threadIdx.x;
  const int row = 512 + (blk & 63) * 16 + (l & 15);
  const int c0 = (blk >> 6) * 32 + (l >> 4) * 8;
  const float* src = qkv_w + (size_t)row * 256 + c0;
  union { unsigned short s[8]; u32x4 v; } u;
#pragma unroll
  for (int j = 0; j < 8; ++j) u.s[j] = f2bf(src[j]);
  *(u32x4*)(wf + ((size_t)blk * 64 + l) * 8) = u.v;
}

// ---------------- fused KV-GEMM + exp + in-register context ----------------
// 1 head/block, 1024 rows/block (512 blocks). All xa fragments from global
// (L2-shared by the 8 same-chunk head-blocks on one XCD). LDS = 64KB wfrag
// (reused for 2-round ctx dump) + 2KB srow -> 2 blocks/CU, 4 waves/SIMD.
// asm memory clobber between K and V phases prevents the compiler from
// CSE-keeping the 16 xa fragments live across phases (round-14's spill cause).
__launch_bounds__(512, 1)
__global__ void k_kvctx(const unsigned short* __restrict__ xnf,
                        const unsigned short* __restrict__ wfrag,
                        const float* __restrict__ qkv_b,
                        float* __restrict__ sump, float* __restrict__ ctxp) {
  __shared__ __align__(16) char lds[67584];    // 64KB wfrag/dump + 2KB srow
  const int t = threadIdx.x;
  const int w = t >> 6, l = t & 63;
  const int q = l & 15;
  const int h = blockIdx.x >> 6;               // head 0..7
  const int chunk = blockIdx.x & 63;           // 1024-row chunk; XCD = chunk%8 for all h

  // stage this head's wfrag slice (64 KB) once: [ph][ks][jj][l]
  {
    const u32x4* wsrc = (const u32x4*)wfrag;
    u32x4* wdst = (u32x4*)lds;
#pragma unroll
    for (int r = 0; r < 8; ++r) {
      const int e = r * 512 + t;
      const int entry = e >> 6, l2 = e & 63;
      const int ph = entry >> 5, ks = (entry >> 2) & 7, jj = entry & 3;
      wdst[e] = wsrc[((size_t)(ks * 64 + ph * 32 + h * 4 + jj)) * 64 + l2];
    }
  }
  __syncthreads();

  const f32x4 fz = {0.f, 0.f, 0.f, 0.f};
  f32x4 ctxa[4][4];
#pragma unroll
  for (int a = 0; a < 4; ++a)
#pragma unroll
    for (int b = 0; b < 4; ++b) ctxa[a][b] = fz;
  float srow[4] = {0.f, 0.f, 0.f, 0.f};
  float bk[4], bv[4];
#pragma unroll
  for (int jj = 0; jj < 4; ++jj) {
    bk[jj] = qkv_b[512 + h * 64 + jj * 16 + q];
    bv[jj] = qkv_b[1024 + h * 64 + jj * 16 + q];
  }

  const u32x4* xnf4 = (const u32x4*)xnf;

  for (int st = 0; st < 4; ++st) {
    const size_t rg0 = (size_t)chunk * 64 + st * 16;   // 16 row-groups / super-tile
    const u32x4* gA = xnf4 + (rg0 + w) * 512 + l;
    const u32x4* gB = xnf4 + (rg0 + 8 + w) * 512 + l;

    // K phase: both groups share the bwk LDS reads
    f32x4 ak[2][4] = {{fz, fz, fz, fz}, {fz, fz, fz, fz}};
#pragma unroll
    for (int ks = 0; ks < 8; ++ks) {
      const bf16x8 xaA = *(const bf16x8*)(gA + ks * 64);
      const bf16x8 xaB = *(const bf16x8*)(gB + ks * 64);
#pragma unroll
      for (int jj = 0; jj < 4; ++jj) {
        const bf16x8 bwk = *(const bf16x8*)(lds + ((ks * 4 + jj) * 64 + l) * 16);
        ak[0][jj] = __builtin_amdgcn_mfma_f32_16x16x32_bf16(xaA, bwk, ak[0][jj], 0, 0, 0);
        ak[1][jj] = __builtin_amdgcn_mfma_f32_16x16x32_bf16(xaB, bwk, ak[1][jj], 0, 0, 0);
      }
    }
    bf16x8 pk[4];
#pragma unroll
    for (int jj = 0; jj < 4; ++jj) {
      float s = 0.f;
      bf16x8 p;
#pragma unroll
      for (int r = 0; r < 4; ++r) {
        const unsigned short u0 = f2bf(__expf(ak[0][jj][r] + bk[jj]));
        const unsigned short u1 = f2bf(__expf(ak[1][jj][r] + bk[jj]));
        p[r] = (short)u0; p[r + 4] = (short)u1;
        s += bf2f(u0) + bf2f(u1);
      }
      pk[jj] = p;
      srow[jj] += s;
    }

    // prevent xa-fragment CSE across phases (would add 64 live VGPRs -> spill)
    asm volatile("" ::: "memory");

    // V phase (re-issues the same loads; L2-hot)
    f32x4 av[2][4] = {{fz, fz, fz, fz}, {fz, fz, fz, fz}};
#pragma unroll
    for (int ks = 0; ks < 8; ++ks) {
      const bf16x8 xaA = *(const bf16x8*)(gA + ks * 64);
      const bf16x8 xaB = *(const bf16x8*)(gB + ks * 64);
#pragma unroll
      for (int jj = 0; jj < 4; ++jj) {
        const bf16x8 bwv = *(const bf16x8*)(lds + (((8 + ks) * 4 + jj) * 64 + l) * 16);
        av[0][jj] = __builtin_amdgcn_mfma_f32_16x16x32_bf16(xaA, bwv, av[0][jj], 0, 0, 0);
        av[1][jj] = __builtin_amdgcn_mfma_f32_16x16x32_bf16(xaB, bwv, av[1][jj], 0, 0, 0);
      }
    }
    bf16x8 pv[4];
#pragma unroll
    for (int jj = 0; jj < 4; ++jj) {
      bf16x8 p;
#pragma unroll
      for (int r = 0; r < 4; ++r) {
        p[r]     = (short)f2bf(av[0][jj][r] + bv[jj]);
        p[r + 4] = (short)f2bf(av[1][jj][r] + bv[jj]);
      }
      pv[jj] = p;
    }

    // context accumulate: full K=32 (both groups)
#pragma unroll
    for (int ja = 0; ja < 4; ++ja)
#pragma unroll
      for (int jb = 0; jb < 4; ++jb)
        ctxa[ja][jb] = __builtin_amdgcn_mfma_f32_16x16x32_bf16(pk[ja], pv[jb], ctxa[ja][jb], 0, 0, 0);
  }

  // ---- block-level reduction: srow + 2-round ctx dump through retired wfrag LDS ----
  __syncthreads();                 // all waves done reading wfrag
  {
    float* srl = (float*)(lds + 65536);
#pragma unroll
    for (int jj = 0; jj < 4; ++jj) {
      float s = srow[jj];
      s += __shfl_xor(s, 16, 64);
      s += __shfl_xor(s, 32, 64);
      if (l < 16) srl[w * 64 + jj * 16 + q] = s;
    }
  }
  // round A: waves 0..3 dump
  if (w < 4) {
    float* dw = (float*)lds + w * 4096 + l * 4;
#pragma unroll
    for (int ja = 0; ja < 4; ++ja)
#pragma unroll
      for (int jb = 0; jb < 4; ++jb)
        *(f32x4*)(dw + (ja * 4 + jb) * 256) = ctxa[ja][jb];
  }
  __syncthreads();
  f32x4 part0 = fz, part1 = fz;
  {
    const float* dump = (const float*)lds;
#pragma unroll
    for (int w4 = 0; w4 < 4; ++w4) {
      part0 += *(const f32x4*)(dump + w4 * 4096 + t * 4);
      part1 += *(const f32x4*)(dump + w4 * 4096 + (512 + t) * 4);
    }
  }
  __syncthreads();
  // round B: waves 4..7 dump
  if (w >= 4) {
    float* dw = (float*)lds + (w - 4) * 4096 + l * 4;
#pragma unroll
    for (int ja = 0; ja < 4; ++ja)
#pragma unroll
      for (int jb = 0; jb < 4; ++jb)
        *(f32x4*)(dw + (ja * 4 + jb) * 256) = ctxa[ja][jb];
  }
  __syncthreads();
  {
    const float* dump = (const float*)lds;
#pragma unroll
    for (int w4 = 0; w4 < 4; ++w4) {
      part0 += *(const f32x4*)(dump + w4 * 4096 + t * 4);
      part1 += *(const f32x4*)(dump + w4 * 4096 + (512 + t) * 4);
    }
    float* cp = ctxp + (size_t)blockIdx.x * 4096;
    *(f32x4*)(cp + t * 4) = part0;
    *(f32x4*)(cp + (512 + t) * 4) = part1;
    if (t < 64) {
      const float* srl = (const float*)(lds + 65536);
      float s = 0.f;
#pragma unroll
      for (int w8 = 0; w8 < 8; ++w8) s += srl[w8 * 64 + t];
      sump[(size_t)(h * 64 + t) * 64 + chunk] = s;
    }
  }
}

// ---------------- reduce partials over 64 chunks (EXACTLY 68 blocks!) ----------------
__global__ void k_ctxred(const float* __restrict__ ctxp, const float* __restrict__ sump,
                         float* __restrict__ ctx, float* __restrict__ sexp) {
  const int t = threadIdx.x;
  if (blockIdx.x < 64) {
    const int m4 = blockIdx.x * 128 + t;     // 0..8192
    const int h = m4 >> 10, p4 = m4 & 1023;
    f32x4 s = {0.f, 0.f, 0.f, 0.f};
#pragma unroll 8
    for (int c = 0; c < 64; ++c)
      s += *(const f32x4*)(ctxp + (((size_t)h * 64 + c) * 1024 + p4) * 4);
    const int jajb = p4 >> 6, ll = p4 & 63;
    const int ja = jajb >> 2, jb = jajb & 3;
    const int gg = ll >> 4, qq = ll & 15;
    float* cw = ctx + ((size_t)h * 64 + ja * 16 + gg * 4) * 64 + jb * 16 + qq;
    cw[0] = s[0]; cw[64] = s[1]; cw[128] = s[2]; cw[192] = s[3];
  } else {
    const int r = (blockIdx.x - 64) * 128 + t;
    float s = 0.f;
#pragma unroll 8
    for (int c = 0; c < 64; ++c) s += sump[(size_t)r * 64 + c];
    sexp[r] = s;
  }
}

// ---------------- W2 ----------------
__global__ void k_w2(const float* __restrict__ out_w, const float* __restrict__ ctx,
                     const float* __restrict__ sexp, float* __restrict__ w2) {
  const int r = blockIdx.x;
  const int h = r >> 6, d = r & 63;
  __shared__ float row[64];
  __shared__ float sinv;
  const int t = threadIdx.x;
  if (t < 64) row[t] = ctx[((size_t)h * 64 + d) * 64 + t];
  if (t == 0) sinv = 1.0f / sexp[r];
  __syncthreads();
  float a = 0.f;
  const float* wp = out_w + (size_t)t * 512 + h * 64;
#pragma unroll 8
  for (int e = 0; e < 64; ++e) a += wp[e] * row[e];
  w2[(size_t)t * 512 + r] = a * sinv;
}

// ---------------- Weff = W2 @ Wq  (+ beff folded in) ----------------
__global__ void k_weff(const float* __restrict__ w2, const float* __restrict__ qkv_w,
                       const float* __restrict__ qkv_b, const float* __restrict__ out_b,
                       float* __restrict__ weff, float* __restrict__ beff) {
  const int o = blockIdx.x;
  const int c = threadIdx.x;
  __shared__ float row[512];
  __shared__ float red[256];
  row[c] = w2[(size_t)o * 512 + c];
  row[256 + c] = w2[(size_t)o * 512 + 256 + c];
  __syncthreads();
  float a = 0.f;
#pragma unroll 8
  for (int r = 0; r < 512; ++r) a += row[r] * qkv_w[(size_t)r * 256 + c];
  weff[o * 256 + c] = a;
  red[c] = row[c] * qkv_b[c] + row[256 + c] * qkv_b[256 + c];
  __syncthreads();
  for (int st = 128; st > 0; st >>= 1) {
    if (c < st) red[c] += red[c + st];
    __syncthreads();
  }
  if (c == 0) beff[o] = out_b[o] + red[0];
}

// ---------------- Weff -> fragment order ----------------
__global__ void k_wefrag(const float* __restrict__ weff, unsigned short* __restrict__ wf) {
  const int blk = blockIdx.x;
  const int l = threadIdx.x;
  const int row = (blk & 15) * 16 + (l & 15);
  const int c0 = (blk >> 4) * 32 + (l >> 4) * 8;
  const float* src = weff + (size_t)row * 256 + c0;
  union { unsigned short s[8]; u32x4 v; } u;
#pragma unroll
  for (int j = 0; j < 8; ++j) u.s[j] = f2bf(src[j]);
  *(u32x4*)(wf + ((size_t)blk * 64 + l) * 8) = u.v;
}

// ---------------- final GEMM (reads xnf fragments) + coalesced epilogue ----------------
__launch_bounds__(256, 2)
__global__ void k_final(const unsigned short* __restrict__ xnf,
                        const unsigned short* __restrict__ wef,
                        const float* __restrict__ beff,
                        float* __restrict__ out) {
  __shared__ unsigned short xlds[32768];   // 64 KB fragment staging, reused for transpose
  const int t = threadIdx.x;
  const int w = t >> 6, l = t & 63;
  const int q = l & 15, g = l >> 4;
  const int si = w >> 1, sj = w & 1;
  // XCD swizzle: each XCD (bid%8) owns a contiguous 8192-column span of every row
  const int bid = (blockIdx.x & 7) * 64 + (blockIdx.x >> 3);
  const size_t n0 = (size_t)bid * 128;
  {
    const u32x4* gs = (const u32x4*)xnf + (size_t)bid * 4096;
    u32x4* ld = (u32x4*)xlds;
#pragma unroll
    for (int k2 = 0; k2 < 16; ++k2)
      ld[t + 256 * k2] = gs[t + 256 * k2];
  }
  __syncthreads();
  const f32x4 fz = {0.f, 0.f, 0.f, 0.f};
  f32x4 acc[4][8];
#pragma unroll
  for (int i = 0; i < 4; ++i)
#pragma unroll
    for (int j = 0; j < 8; ++j) acc[i][j] = fz;
#pragma unroll
  for (int ks = 0; ks < 8; ++ks) {
    bf16x8 xa[4];
#pragma unroll
    for (int i = 0; i < 4; ++i)
      xa[i] = *(const bf16x8*)((const char*)xlds + (((si * 4 + i) * 8 + ks) * 64 + l) * 16);
#pragma unroll
    for (int jj = 0; jj < 8; ++jj) {
      const bf16x8 bw = *(const bf16x8*)(wef + (((size_t)(ks * 16 + sj * 8 + jj)) * 64 + l) * 8);
#pragma unroll
      for (int i = 0; i < 4; ++i)
        acc[i][jj] = __builtin_amdgcn_mfma_f32_16x16x32_bf16(xa[i], bw, acc[i][jj], 0, 0, 0);
    }
  }
  // transpose epilogue through LDS: 4 rounds of 64 output rows
  __syncthreads();
  float* trf = (float*)xlds;               // [64][129] floats
#pragma unroll
  for (int k4 = 0; k4 < 4; ++k4) {
    if ((k4 >> 1) == sj) {
#pragma unroll
      for (int jj2 = 0; jj2 < 4; ++jj2) {
        const int jj = (k4 & 1) * 4 + jj2;
        const float be = beff[sj * 128 + jj * 16 + q];
#pragma unroll
        for (int i = 0; i < 4; ++i)
#pragma unroll
          for (int r = 0; r < 4; ++r)
            trf[(jj2 * 16 + q) * 129 + si * 64 + i * 16 + g * 4 + r] = acc[i][jj][r] + be;
      }
    }
    __syncthreads();
#pragma unroll
    for (int j = 0; j < 32; ++j) {
      const int mm = j * 256 + t;          // 8192 floats
      const int ol = mm >> 7, cc = mm & 127;
      out[(size_t)(k4 * 64 + ol) * NSP + n0 + cc] = trf[ol * 129 + cc];
    }
    __syncthreads();
  }
}

extern "C" void kernel_launch(void* const* d_in, const int* in_sizes, int n_in,
                              void* d_out, int out_size, void* d_ws, size_t ws_size,
                              hipStream_t stream) {
  const float* x     = (const float*)d_in[0];
  const float* gn_w  = (const float*)d_in[1];
  const float* gn_b  = (const float*)d_in[2];
  const float* qkv_w = (const float*)d_in[3];
  const float* qkv_b = (const float*)d_in[4];
  const float* out_w = (const float*)d_in[5];
  const float* out_b = (const float*)d_in[6];
  char* ws = (char*)d_ws;
  unsigned short* xnf = (unsigned short*)(ws + WS_XN);
  unsigned short* wf  = (unsigned short*)(ws + WS_WFRAG);
  unsigned short* wef = (unsigned short*)(ws + WS_WEFRAG);
  float* part   = (float*)(ws + WS_PART);   // stats partials, then sexp[512]
  float* ab     = (float*)(ws + WS_AB);
  float* ctx    = (float*)(ws + WS_CTX);
  float* w2     = (float*)(ws + WS_W2);
  float* weff   = (float*)(ws + WS_WEFF);
  float* beff   = (float*)(ws + WS_BEFF);
  float* out    = (float*)d_out;
  // d_out scratch (consumed by k_ctxred before k_final writes out):
  float* ctxp = (float*)((char*)d_out + 33554432ULL);       //  8 MB
  float* sump = (float*)((char*)d_out + 41943040ULL);       // 128 KB

  k_wfrag<<<512, 64, 0, stream>>>(qkv_w, wf);
  k_stats<<<256, 256, 0, stream>>>(x, part);
  k_coef<<<1, 256, 0, stream>>>(part, gn_w, gn_b, ab);
  k_xn<<<dim3(1024, 4), 256, 0, stream>>>(x, ab, xnf);
  k_kvctx<<<512, 512, 0, stream>>>(xnf, wf, qkv_b, sump, ctxp);
  k_ctxred<<<68, 128, 0, stream>>>(ctxp, sump, ctx, part);
  k_w2<<<512, 256, 0, stream>>>(out_w, ctx, part, w2);
  k_weff<<<256, 256, 0, stream>>>(w2, qkv_w, qkv_b, out_b, weff, beff);
  k_wefrag<<<128, 64, 0, stream>>>(weff, wef);
  k_final<<<512, 256, 0, stream>>>(xnf, wef, beff, out);
}

// Round 21
// 172.857 us; speedup vs baseline: 1.0036x; 1.0036x over previous
//
#include <hip/hip_runtime.h>
#include <stdint.h>

typedef __attribute__((ext_vector_type(8))) short bf16x8;
typedef __attribute__((ext_vector_type(4))) float f32x4;
typedef __attribute__((ext_vector_type(4))) unsigned int u32x4;

#define NSP 65536

// workspace byte offsets
#define WS_XN     0ULL         // 33554432  bf16 xf = bf16(x) fragment-native
#define WS_WFRAG  33554432ULL  // 524288    a-scaled Wkv fragment buffer
#define WS_WEFRAG 34078720ULL  // 131072    a-scaled Weff fragment buffer
#define WS_PART   34209792ULL  // 2048      sexp[512]
#define WS_AB     34211840ULL  // 2048      per-channel a,b
#define WS_CTX    34215936ULL  // 131072    ctx[8][64][64]
#define WS_W2     34347008ULL  // 1048576   W2[256][512]
#define WS_WEFF   35395584ULL  // 262144    Weff[256][256]
#define WS_BEFF   35657728ULL  // 1024      beff[256]
#define WS_BQV    35658752ULL  // 6144      b-folded qkv biases [1536]

// d_out scratch (consumed before k_final overwrites d_out):
//   ctxp (f32) [32MB..40MB)   512 blocks * 4096 partials
//   sump (f32) [40MB..+128KB) [h*64+d][chunk64]
//   p2s  (f32) [44MB..+1MB)   per-channel partial sums [256][1024]
//   p2q  (f32) [45MB..+1MB)   per-channel partial sumsq

__device__ __forceinline__ unsigned short f2bf(float f) {
  union { float f; uint32_t u; } v; v.f = f;
  uint32_t r = v.u + 0x7FFFu + ((v.u >> 16) & 1u);
  return (unsigned short)(r >> 16);
}
__device__ __forceinline__ float bf2f(unsigned short b) {
  union { uint32_t u; float f; } v; v.u = ((uint32_t)b) << 16;
  return v.f;
}

// ---------------- fused: cast+transpose to fragments + per-channel stats ----------------
__global__ void k_xnstats(const float* __restrict__ x, unsigned short* __restrict__ xf,
                          float* __restrict__ p2s, float* __restrict__ p2q) {
  __shared__ float tile[64][66];
  const int t = threadIdx.x;
  const int nb = blockIdx.x, cb = blockIdx.y;
  {
    const int cl = t >> 2, nc = t & 3;
    const int c = cb * 64 + cl;
    const f32x4* src = (const f32x4*)(x + (size_t)c * NSP + nb * 64 + nc * 16);
    float s = 0.f, qq = 0.f;
#pragma unroll
    for (int j = 0; j < 4; ++j) {
      f32x4 v = __builtin_nontemporal_load(src + j);
      *(f32x4*)&tile[cl][nc * 16 + j * 4] = v;
      s  += v[0] + v[1] + v[2] + v[3];
      qq += v[0] * v[0] + v[1] * v[1] + v[2] * v[2] + v[3] * v[3];
    }
    // reduce the 4 lanes (nc 0..3) that share channel cl
    s  += __shfl_xor(s, 1, 64);  s  += __shfl_xor(s, 2, 64);
    qq += __shfl_xor(qq, 1, 64); qq += __shfl_xor(qq, 2, 64);
    if (nc == 0) {
      p2s[(size_t)(cb * 64 + cl) * 1024 + nb] = s;
      p2q[(size_t)(cb * 64 + cl) * 1024 + nb] = qq;
    }
  }
  __syncthreads();
  {
    const int l = t & 63, w0 = t >> 6;
    u32x4* xf4 = (u32x4*)xf;
#pragma unroll
    for (int u2 = 0; u2 < 2; ++u2) {
      const int fp = w0 + u2 * 4;          // 0..7
      const int fl = fp >> 1, ksl = fp & 1;
      union { unsigned short s[8]; u32x4 v; } pk2;
#pragma unroll
      for (int e = 0; e < 8; ++e)
        pk2.s[e] = f2bf(tile[ksl * 32 + (l >> 4) * 8 + e][fl * 16 + (l & 15)]);
      xf4[((size_t)(nb * 4 + fl) * 8 + cb * 2 + ksl) * 64 + l] = pk2.v;
    }
  }
}

// ---------------- group stats -> per-channel a,b (one block per group of 8 ch) ----------------
__global__ void k_coefg(const float* __restrict__ p2s, const float* __restrict__ p2q,
                        const float* __restrict__ gn_w, const float* __restrict__ gn_b,
                        float* __restrict__ ab) {
  __shared__ float rs[256], rq[256];
  const int g = blockIdx.x, t = threadIdx.x;
  const float* ps = p2s + (size_t)g * 8192;
  const float* pq = p2q + (size_t)g * 8192;
  float s = 0.f, q = 0.f;
  for (int i = t; i < 8192; i += 256) { s += ps[i]; q += pq[i]; }
  rs[t] = s; rq[t] = q;
  __syncthreads();
  for (int st = 128; st > 0; st >>= 1) {
    if (t < st) { rs[t] += rs[t + st]; rq[t] += rq[t + st]; }
    __syncthreads();
  }
  if (t < 8) {
    const int c = g * 8 + t;
    const float inv = 1.0f / 524288.0f;
    const float mean = rs[0] * inv;
    const float var = rq[0] * inv - mean * mean;
    const float rstd = rsqrtf(var + 1e-5f);
    const float a = gn_w[c] * rstd;
    ab[c] = a;
    ab[256 + c] = gn_b[c] - mean * a;
  }
}

// ---------------- a-scaled Wkv rows -> MFMA B-fragment order ----------------
__global__ void k_wfrag(const float* __restrict__ qkv_w, const float* __restrict__ ab,
                        unsigned short* __restrict__ wf) {
  const int blk = blockIdx.x;                 // blk = ks*64 + cf
  const int l = threadIdx.x;
  const int row = 512 + (blk & 63) * 16 + (l & 15);
  const int c0 = (blk >> 6) * 32 + (l >> 4) * 8;
  const float* src = qkv_w + (size_t)row * 256 + c0;
  union { unsigned short s[8]; u32x4 v; } u;
#pragma unroll
  for (int j = 0; j < 8; ++j) u.s[j] = f2bf(src[j] * ab[c0 + j]);
  *(u32x4*)(wf + ((size_t)blk * 64 + l) * 8) = u.v;
}

// ---------------- b-folded biases: bqv[r] = qkv_b[r] + sum_c qkv_w[r][c]*b_c ----------------
__global__ void k_bkv(const float* __restrict__ qkv_w, const float* __restrict__ qkv_b,
                      const float* __restrict__ ab, float* __restrict__ bqv) {
  const int l = threadIdx.x;
  const int r = blockIdx.x * 4 + (l >> 4);    // 384 blocks * 4 rows
  const int li = l & 15;
  const float* wr = qkv_w + (size_t)r * 256 + li * 16;
  float s = 0.f;
#pragma unroll
  for (int j = 0; j < 16; ++j) s += wr[j] * ab[256 + li * 16 + j];
  s += __shfl_xor(s, 1, 64);
  s += __shfl_xor(s, 2, 64);
  s += __shfl_xor(s, 4, 64);
  s += __shfl_xor(s, 8, 64);
  if (li == 0) bqv[r] = qkv_b[r] + s;
}

// ---------------- fused KV-GEMM + exp + in-register context (frozen @63us) ----------------
__launch_bounds__(512, 1)
__global__ void k_kvctx(const unsigned short* __restrict__ xf,
                        const unsigned short* __restrict__ wfrag,
                        const float* __restrict__ bqv,
                        float* __restrict__ sump, float* __restrict__ ctxp) {
  __shared__ __align__(16) char lds[67584];    // 64KB wfrag/dump + 2KB srow
  const int t = threadIdx.x;
  const int w = t >> 6, l = t & 63;
  const int q = l & 15;
  const int h = blockIdx.x >> 6;               // head 0..7
  const int chunk = blockIdx.x & 63;           // 1024-row chunk; XCD = chunk%8 for all h

  {
    const u32x4* wsrc = (const u32x4*)wfrag;
    u32x4* wdst = (u32x4*)lds;
#pragma unroll
    for (int r = 0; r < 8; ++r) {
      const int e = r * 512 + t;
      const int entry = e >> 6, l2 = e & 63;
      const int ph = entry >> 5, ks = (entry >> 2) & 7, jj = entry & 3;
      wdst[e] = wsrc[((size_t)(ks * 64 + ph * 32 + h * 4 + jj)) * 64 + l2];
    }
  }
  __syncthreads();

  const f32x4 fz = {0.f, 0.f, 0.f, 0.f};
  f32x4 ctxa[4][4];
#pragma unroll
  for (int a = 0; a < 4; ++a)
#pragma unroll
    for (int b = 0; b < 4; ++b) ctxa[a][b] = fz;
  float srow[4] = {0.f, 0.f, 0.f, 0.f};
  float bk[4], bv[4];
#pragma unroll
  for (int jj = 0; jj < 4; ++jj) {
    bk[jj] = bqv[512 + h * 64 + jj * 16 + q];
    bv[jj] = bqv[1024 + h * 64 + jj * 16 + q];
  }

  const u32x4* xf4 = (const u32x4*)xf;

  for (int st = 0; st < 4; ++st) {
    const size_t rg0 = (size_t)chunk * 64 + st * 16;
    const u32x4* gA = xf4 + (rg0 + w) * 512 + l;
    const u32x4* gB = xf4 + (rg0 + 8 + w) * 512 + l;

    f32x4 ak[2][4] = {{fz, fz, fz, fz}, {fz, fz, fz, fz}};
#pragma unroll
    for (int ks = 0; ks < 8; ++ks) {
      const bf16x8 xaA = *(const bf16x8*)(gA + ks * 64);
      const bf16x8 xaB = *(const bf16x8*)(gB + ks * 64);
#pragma unroll
      for (int jj = 0; jj < 4; ++jj) {
        const bf16x8 bwk = *(const bf16x8*)(lds + ((ks * 4 + jj) * 64 + l) * 16);
        ak[0][jj] = __builtin_amdgcn_mfma_f32_16x16x32_bf16(xaA, bwk, ak[0][jj], 0, 0, 0);
        ak[1][jj] = __builtin_amdgcn_mfma_f32_16x16x32_bf16(xaB, bwk, ak[1][jj], 0, 0, 0);
      }
    }
    bf16x8 pk[4];
#pragma unroll
    for (int jj = 0; jj < 4; ++jj) {
      float s = 0.f;
      bf16x8 p;
#pragma unroll
      for (int r = 0; r < 4; ++r) {
        const unsigned short u0 = f2bf(__expf(ak[0][jj][r] + bk[jj]));
        const unsigned short u1 = f2bf(__expf(ak[1][jj][r] + bk[jj]));
        p[r] = (short)u0; p[r + 4] = (short)u1;
        s += bf2f(u0) + bf2f(u1);
      }
      pk[jj] = p;
      srow[jj] += s;
    }

    asm volatile("" ::: "memory");   // block xa-fragment CSE across phases (spill guard)

    f32x4 av[2][4] = {{fz, fz, fz, fz}, {fz, fz, fz, fz}};
#pragma unroll
    for (int ks = 0; ks < 8; ++ks) {
      const bf16x8 xaA = *(const bf16x8*)(gA + ks * 64);
      const bf16x8 xaB = *(const bf16x8*)(gB + ks * 64);
#pragma unroll
      for (int jj = 0; jj < 4; ++jj) {
        const bf16x8 bwv = *(const bf16x8*)(lds + (((8 + ks) * 4 + jj) * 64 + l) * 16);
        av[0][jj] = __builtin_amdgcn_mfma_f32_16x16x32_bf16(xaA, bwv, av[0][jj], 0, 0, 0);
        av[1][jj] = __builtin_amdgcn_mfma_f32_16x16x32_bf16(xaB, bwv, av[1][jj], 0, 0, 0);
      }
    }
    bf16x8 pv[4];
#pragma unroll
    for (int jj = 0; jj < 4; ++jj) {
      bf16x8 p;
#pragma unroll
      for (int r = 0; r < 4; ++r) {
        p[r]     = (short)f2bf(av[0][jj][r] + bv[jj]);
        p[r + 4] = (short)f2bf(av[1][jj][r] + bv[jj]);
      }
      pv[jj] = p;
    }

#pragma unroll
    for (int ja = 0; ja < 4; ++ja)
#pragma unroll
      for (int jb = 0; jb < 4; ++jb)
        ctxa[ja][jb] = __builtin_amdgcn_mfma_f32_16x16x32_bf16(pk[ja], pv[jb], ctxa[ja][jb], 0, 0, 0);
  }

  __syncthreads();
  {
    float* srl = (float*)(lds + 65536);
#pragma unroll
    for (int jj = 0; jj < 4; ++jj) {
      float s = srow[jj];
      s += __shfl_xor(s, 16, 64);
      s += __shfl_xor(s, 32, 64);
      if (l < 16) srl[w * 64 + jj * 16 + q] = s;
    }
  }
  if (w < 4) {
    float* dw = (float*)lds + w * 4096 + l * 4;
#pragma unroll
    for (int ja = 0; ja < 4; ++ja)
#pragma unroll
      for (int jb = 0; jb < 4; ++jb)
        *(f32x4*)(dw + (ja * 4 + jb) * 256) = ctxa[ja][jb];
  }
  __syncthreads();
  f32x4 part0 = fz, part1 = fz;
  {
    const float* dump = (const float*)lds;
#pragma unroll
    for (int w4 = 0; w4 < 4; ++w4) {
      part0 += *(const f32x4*)(dump + w4 * 4096 + t * 4);
      part1 += *(const f32x4*)(dump + w4 * 4096 + (512 + t) * 4);
    }
  }
  __syncthreads();
  if (w >= 4) {
    float* dw = (float*)lds + (w - 4) * 4096 + l * 4;
#pragma unroll
    for (int ja = 0; ja < 4; ++ja)
#pragma unroll
      for (int jb = 0; jb < 4; ++jb)
        *(f32x4*)(dw + (ja * 4 + jb) * 256) = ctxa[ja][jb];
  }
  __syncthreads();
  {
    const float* dump = (const float*)lds;
#pragma unroll
    for (int w4 = 0; w4 < 4; ++w4) {
      part0 += *(const f32x4*)(dump + w4 * 4096 + t * 4);
      part1 += *(const f32x4*)(dump + w4 * 4096 + (512 + t) * 4);
    }
    float* cp = ctxp + (size_t)blockIdx.x * 4096;
    *(f32x4*)(cp + t * 4) = part0;
    *(f32x4*)(cp + (512 + t) * 4) = part1;
    if (t < 64) {
      const float* srl = (const float*)(lds + 65536);
      float s = 0.f;
#pragma unroll
      for (int w8 = 0; w8 < 8; ++w8) s += srl[w8 * 64 + t];
      sump[(size_t)(h * 64 + t) * 64 + chunk] = s;
    }
  }
}

// ---------------- reduce partials over 64 chunks (EXACTLY 68 blocks) ----------------
__global__ void k_ctxred(const float* __restrict__ ctxp, const float* __restrict__ sump,
                         float* __restrict__ ctx, float* __restrict__ sexp) {
  const int t = threadIdx.x;
  if (blockIdx.x < 64) {
    const int m4 = blockIdx.x * 128 + t;
    const int h = m4 >> 10, p4 = m4 & 1023;
    f32x4 s = {0.f, 0.f, 0.f, 0.f};
#pragma unroll 8
    for (int c = 0; c < 64; ++c)
      s += *(const f32x4*)(ctxp + (((size_t)h * 64 + c) * 1024 + p4) * 4);
    const int jajb = p4 >> 6, ll = p4 & 63;
    const int ja = jajb >> 2, jb = jajb & 3;
    const int gg = ll >> 4, qq = ll & 15;
    float* cw = ctx + ((size_t)h * 64 + ja * 16 + gg * 4) * 64 + jb * 16 + qq;
    cw[0] = s[0]; cw[64] = s[1]; cw[128] = s[2]; cw[192] = s[3];
  } else {
    const int r = (blockIdx.x - 64) * 128 + t;
    float s = 0.f;
#pragma unroll 8
    for (int c = 0; c < 64; ++c) s += sump[(size_t)r * 64 + c];
    sexp[r] = s;
  }
}

// ---------------- W2 ----------------
__global__ void k_w2(const float* __restrict__ out_w, const float* __restrict__ ctx,
                     const float* __restrict__ sexp, float* __restrict__ w2) {
  const int r = blockIdx.x;
  const int h = r >> 6, d = r & 63;
  __shared__ float row[64];
  __shared__ float sinv;
  const int t = threadIdx.x;
  if (t < 64) row[t] = ctx[((size_t)h * 64 + d) * 64 + t];
  if (t == 0) sinv = 1.0f / sexp[r];
  __syncthreads();
  float a = 0.f;
  const float* wp = out_w + (size_t)t * 512 + h * 64;
#pragma unroll 8
  for (int e = 0; e < 64; ++e) a += wp[e] * row[e];
  w2[(size_t)t * 512 + r] = a * sinv;
}

// ---------------- Weff = W2 @ Wq  (+ beff with b-folded q bias) ----------------
__global__ void k_weff(const float* __restrict__ w2, const float* __restrict__ qkv_w,
                       const float* __restrict__ bqv, const float* __restrict__ out_b,
                       float* __restrict__ weff, float* __restrict__ beff) {
  const int o = blockIdx.x;
  const int c = threadIdx.x;
  __shared__ float row[512];
  __shared__ float red[256];
  row[c] = w2[(size_t)o * 512 + c];
  row[256 + c] = w2[(size_t)o * 512 + 256 + c];
  __syncthreads();
  float a = 0.f;
#pragma unroll 8
  for (int r = 0; r < 512; ++r) a += row[r] * qkv_w[(size_t)r * 256 + c];
  weff[o * 256 + c] = a;
  red[c] = row[c] * bqv[c] + row[256 + c] * bqv[256 + c];
  __syncthreads();
  for (int st = 128; st > 0; st >>= 1) {
    if (c < st) red[c] += red[c + st];
    __syncthreads();
  }
  if (c == 0) beff[o] = out_b[o] + red[0];
}

// ---------------- a-scaled Weff -> fragment order ----------------
__global__ void k_wefrag(const float* __restrict__ weff, const float* __restrict__ ab,
                         unsigned short* __restrict__ wf) {
  const int blk = blockIdx.x;
  const int l = threadIdx.x;
  const int row = (blk & 15) * 16 + (l & 15);
  const int c0 = (blk >> 4) * 32 + (l >> 4) * 8;
  const float* src = weff + (size_t)row * 256 + c0;
  union { unsigned short s[8]; u32x4 v; } u;
#pragma unroll
  for (int j = 0; j < 8; ++j) u.s[j] = f2bf(src[j] * ab[c0 + j]);
  *(u32x4*)(wf + ((size_t)blk * 64 + l) * 8) = u.v;
}

// ---------------- final GEMM (reads xf fragments) + coalesced epilogue ----------------
__launch_bounds__(256, 2)
__global__ void k_final(const unsigned short* __restrict__ xf,
                        const unsigned short* __restrict__ wef,
                        const float* __restrict__ beff,
                        float* __restrict__ out) {
  __shared__ unsigned short xlds[32768];
  const int t = threadIdx.x;
  const int w = t >> 6, l = t & 63;
  const int q = l & 15, g = l >> 4;
  const int si = w >> 1, sj = w & 1;
  const int bid = (blockIdx.x & 7) * 64 + (blockIdx.x >> 3);
  const size_t n0 = (size_t)bid * 128;
  {
    const u32x4* gs = (const u32x4*)xf + (size_t)bid * 4096;
    u32x4* ld = (u32x4*)xlds;
#pragma unroll
    for (int k2 = 0; k2 < 16; ++k2)
      ld[t + 256 * k2] = gs[t + 256 * k2];
  }
  __syncthreads();
  const f32x4 fz = {0.f, 0.f, 0.f, 0.f};
  f32x4 acc[4][8];
#pragma unroll
  for (int i = 0; i < 4; ++i)
#pragma unroll
    for (int j = 0; j < 8; ++j) acc[i][j] = fz;
#pragma unroll
  for (int ks = 0; ks < 8; ++ks) {
    bf16x8 xa[4];
#pragma unroll
    for (int i = 0; i < 4; ++i)
      xa[i] = *(const bf16x8*)((const char*)xlds + (((si * 4 + i) * 8 + ks) * 64 + l) * 16);
#pragma unroll
    for (int jj = 0; jj < 8; ++jj) {
      const bf16x8 bw = *(const bf16x8*)(wef + (((size_t)(ks * 16 + sj * 8 + jj)) * 64 + l) * 8);
#pragma unroll
      for (int i = 0; i < 4; ++i)
        acc[i][jj] = __builtin_amdgcn_mfma_f32_16x16x32_bf16(xa[i], bw, acc[i][jj], 0, 0, 0);
    }
  }
  __syncthreads();
  float* trf = (float*)xlds;
#pragma unroll
  for (int k4 = 0; k4 < 4; ++k4) {
    if ((k4 >> 1) == sj) {
#pragma unroll
      for (int jj2 = 0; jj2 < 4; ++jj2) {
        const int jj = (k4 & 1) * 4 + jj2;
        const float be = beff[sj * 128 + jj * 16 + q];
#pragma unroll
        for (int i = 0; i < 4; ++i)
#pragma unroll
          for (int r = 0; r < 4; ++r)
            trf[(jj2 * 16 + q) * 129 + si * 64 + i * 16 + g * 4 + r] = acc[i][jj][r] + be;
      }
    }
    __syncthreads();
#pragma unroll
    for (int j = 0; j < 32; ++j) {
      const int mm = j * 256 + t;
      const int ol = mm >> 7, cc = mm & 127;
      out[(size_t)(k4 * 64 + ol) * NSP + n0 + cc] = trf[ol * 129 + cc];
    }
    __syncthreads();
  }
}

extern "C" void kernel_launch(void* const* d_in, const int* in_sizes, int n_in,
                              void* d_out, int out_size, void* d_ws, size_t ws_size,
                              hipStream_t stream) {
  const float* x     = (const float*)d_in[0];
  const float* gn_w  = (const float*)d_in[1];
  const float* gn_b  = (const float*)d_in[2];
  const float* qkv_w = (const float*)d_in[3];
  const float* qkv_b = (const float*)d_in[4];
  const float* out_w = (const float*)d_in[5];
  const float* out_b = (const float*)d_in[6];
  char* ws = (char*)d_ws;
  unsigned short* xf  = (unsigned short*)(ws + WS_XN);
  unsigned short* wf  = (unsigned short*)(ws + WS_WFRAG);
  unsigned short* wef = (unsigned short*)(ws + WS_WEFRAG);
  float* sexp   = (float*)(ws + WS_PART);
  float* ab     = (float*)(ws + WS_AB);
  float* ctx    = (float*)(ws + WS_CTX);
  float* w2     = (float*)(ws + WS_W2);
  float* weff   = (float*)(ws + WS_WEFF);
  float* beff   = (float*)(ws + WS_BEFF);
  float* bqv    = (float*)(ws + WS_BQV);
  float* out    = (float*)d_out;
  // d_out scratch (all consumed before k_final writes out):
  float* ctxp = (float*)((char*)d_out + 33554432ULL);       //  8 MB
  float* sump = (float*)((char*)d_out + 41943040ULL);       // 128 KB
  float* p2s  = (float*)((char*)d_out + 46137344ULL);       //  1 MB
  float* p2q  = (float*)((char*)d_out + 47185920ULL);       //  1 MB

  k_xnstats<<<dim3(1024, 4), 256, 0, stream>>>(x, xf, p2s, p2q);
  k_coefg<<<32, 256, 0, stream>>>(p2s, p2q, gn_w, gn_b, ab);
  k_wfrag<<<512, 64, 0, stream>>>(qkv_w, ab, wf);
  k_bkv<<<384, 64, 0, stream>>>(qkv_w, qkv_b, ab, bqv);
  k_kvctx<<<512, 512, 0, stream>>>(xf, wf, bqv, sump, ctxp);
  k_ctxred<<<68, 128, 0, stream>>>(ctxp, sump, ctx, sexp);
  k_w2<<<512, 256, 0, stream>>>(out_w, ctx, sexp, w2);
  k_weff<<<256, 256, 0, stream>>>(w2, qkv_w, bqv, out_b, weff, beff);
  k_wefrag<<<128, 64, 0, stream>>>(weff, ab, wef);
  k_final<<<512, 256, 0, stream>>>(xf, wef, beff, out);
}

// Round 22
// 170.373 us; speedup vs baseline: 1.0182x; 1.0146x over previous
//
#include <hip/hip_runtime.h>
#include <stdint.h>

typedef __attribute__((ext_vector_type(8))) short bf16x8;
typedef __attribute__((ext_vector_type(4))) float f32x4;
typedef __attribute__((ext_vector_type(4))) unsigned int u32x4;

#define NSP 65536

// workspace byte offsets
#define WS_XN     0ULL         // 33554432  bf16 xf = bf16(x) fragment-native
#define WS_WFRAG  33554432ULL  // 524288    a-scaled Wkv fragment buffer
#define WS_WEFRAG 34078720ULL  // 131072    a-scaled Weff fragment buffer
#define WS_AB     34211840ULL  // 2048      per-channel a,b
#define WS_W2     34347008ULL  // 1048576   W2[256][512]
#define WS_BEFF   35657728ULL  // 1024      beff[256]
#define WS_BQV    35658752ULL  // 6144      b-folded qkv biases [1536]

// d_out scratch (consumed before k_final overwrites d_out):
//   ctxp (f32) [32MB..40MB)   512 blocks * 4096 partials
//   sump (f32) [40MB..+128KB) [h*64+d][chunk64]
//   p2s  (f32) [44MB..+1MB)   per-channel partial sums [256][1024]
//   p2q  (f32) [45MB..+1MB)   per-channel partial sumsq

__device__ __forceinline__ unsigned short f2bf(float f) {
  union { float f; uint32_t u; } v; v.f = f;
  uint32_t r = v.u + 0x7FFFu + ((v.u >> 16) & 1u);
  return (unsigned short)(r >> 16);
}
__device__ __forceinline__ float bf2f(unsigned short b) {
  union { uint32_t u; float f; } v; v.u = ((uint32_t)b) << 16;
  return v.f;
}

// ---------------- fused: cast+transpose to fragments + per-channel stats ----------------
__global__ void k_xnstats(const float* __restrict__ x, unsigned short* __restrict__ xf,
                          float* __restrict__ p2s, float* __restrict__ p2q) {
  __shared__ float tile[64][66];
  const int t = threadIdx.x;
  const int nb = blockIdx.x, cb = blockIdx.y;
  {
    const int cl = t >> 2, nc = t & 3;
    const int c = cb * 64 + cl;
    const f32x4* src = (const f32x4*)(x + (size_t)c * NSP + nb * 64 + nc * 16);
    float s = 0.f, qq = 0.f;
#pragma unroll
    for (int j = 0; j < 4; ++j) {
      f32x4 v = __builtin_nontemporal_load(src + j);
      *(f32x4*)&tile[cl][nc * 16 + j * 4] = v;
      s  += v[0] + v[1] + v[2] + v[3];
      qq += v[0] * v[0] + v[1] * v[1] + v[2] * v[2] + v[3] * v[3];
    }
    s  += __shfl_xor(s, 1, 64);  s  += __shfl_xor(s, 2, 64);
    qq += __shfl_xor(qq, 1, 64); qq += __shfl_xor(qq, 2, 64);
    if (nc == 0) {
      p2s[(size_t)(cb * 64 + cl) * 1024 + nb] = s;
      p2q[(size_t)(cb * 64 + cl) * 1024 + nb] = qq;
    }
  }
  __syncthreads();
  {
    const int l = t & 63, w0 = t >> 6;
    u32x4* xf4 = (u32x4*)xf;
#pragma unroll
    for (int u2 = 0; u2 < 2; ++u2) {
      const int fp = w0 + u2 * 4;
      const int fl = fp >> 1, ksl = fp & 1;
      union { unsigned short s[8]; u32x4 v; } pk2;
#pragma unroll
      for (int e = 0; e < 8; ++e)
        pk2.s[e] = f2bf(tile[ksl * 32 + (l >> 4) * 8 + e][fl * 16 + (l & 15)]);
      xf4[((size_t)(nb * 4 + fl) * 8 + cb * 2 + ksl) * 64 + l] = pk2.v;
    }
  }
}

// ---------------- group stats -> per-channel a,b ----------------
__global__ void k_coefg(const float* __restrict__ p2s, const float* __restrict__ p2q,
                        const float* __restrict__ gn_w, const float* __restrict__ gn_b,
                        float* __restrict__ ab) {
  __shared__ float rs[256], rq[256];
  const int g = blockIdx.x, t = threadIdx.x;
  const float* ps = p2s + (size_t)g * 8192;
  const float* pq = p2q + (size_t)g * 8192;
  float s = 0.f, q = 0.f;
  for (int i = t; i < 8192; i += 256) { s += ps[i]; q += pq[i]; }
  rs[t] = s; rq[t] = q;
  __syncthreads();
  for (int st = 128; st > 0; st >>= 1) {
    if (t < st) { rs[t] += rs[t + st]; rq[t] += rq[t + st]; }
    __syncthreads();
  }
  if (t < 8) {
    const int c = g * 8 + t;
    const float inv = 1.0f / 524288.0f;
    const float mean = rs[0] * inv;
    const float var = rq[0] * inv - mean * mean;
    const float rstd = rsqrtf(var + 1e-5f);
    const float a = gn_w[c] * rstd;
    ab[c] = a;
    ab[256 + c] = gn_b[c] - mean * a;
  }
}

// ---------------- a-scaled Wkv rows -> MFMA B-fragment order ----------------
__global__ void k_wfrag(const float* __restrict__ qkv_w, const float* __restrict__ ab,
                        unsigned short* __restrict__ wf) {
  const int blk = blockIdx.x;
  const int l = threadIdx.x;
  const int row = 512 + (blk & 63) * 16 + (l & 15);
  const int c0 = (blk >> 6) * 32 + (l >> 4) * 8;
  const float* src = qkv_w + (size_t)row * 256 + c0;
  union { unsigned short s[8]; u32x4 v; } u;
#pragma unroll
  for (int j = 0; j < 8; ++j) u.s[j] = f2bf(src[j] * ab[c0 + j]);
  *(u32x4*)(wf + ((size_t)blk * 64 + l) * 8) = u.v;
}

// ---------------- b-folded biases ----------------
__global__ void k_bkv(const float* __restrict__ qkv_w, const float* __restrict__ qkv_b,
                      const float* __restrict__ ab, float* __restrict__ bqv) {
  const int l = threadIdx.x;
  const int r = blockIdx.x * 4 + (l >> 4);
  const int li = l & 15;
  const float* wr = qkv_w + (size_t)r * 256 + li * 16;
  float s = 0.f;
#pragma unroll
  for (int j = 0; j < 16; ++j) s += wr[j] * ab[256 + li * 16 + j];
  s += __shfl_xor(s, 1, 64);
  s += __shfl_xor(s, 2, 64);
  s += __shfl_xor(s, 4, 64);
  s += __shfl_xor(s, 8, 64);
  if (li == 0) bqv[r] = qkv_b[r] + s;
}

// ---------------- fused KV-GEMM + exp + in-register context (frozen @63us) ----------------
__launch_bounds__(512, 1)
__global__ void k_kvctx(const unsigned short* __restrict__ xf,
                        const unsigned short* __restrict__ wfrag,
                        const float* __restrict__ bqv,
                        float* __restrict__ sump, float* __restrict__ ctxp) {
  __shared__ __align__(16) char lds[67584];
  const int t = threadIdx.x;
  const int w = t >> 6, l = t & 63;
  const int q = l & 15;
  const int h = blockIdx.x >> 6;
  const int chunk = blockIdx.x & 63;

  {
    const u32x4* wsrc = (const u32x4*)wfrag;
    u32x4* wdst = (u32x4*)lds;
#pragma unroll
    for (int r = 0; r < 8; ++r) {
      const int e = r * 512 + t;
      const int entry = e >> 6, l2 = e & 63;
      const int ph = entry >> 5, ks = (entry >> 2) & 7, jj = entry & 3;
      wdst[e] = wsrc[((size_t)(ks * 64 + ph * 32 + h * 4 + jj)) * 64 + l2];
    }
  }
  __syncthreads();

  const f32x4 fz = {0.f, 0.f, 0.f, 0.f};
  f32x4 ctxa[4][4];
#pragma unroll
  for (int a = 0; a < 4; ++a)
#pragma unroll
    for (int b = 0; b < 4; ++b) ctxa[a][b] = fz;
  float srow[4] = {0.f, 0.f, 0.f, 0.f};
  float bk[4], bv[4];
#pragma unroll
  for (int jj = 0; jj < 4; ++jj) {
    bk[jj] = bqv[512 + h * 64 + jj * 16 + q];
    bv[jj] = bqv[1024 + h * 64 + jj * 16 + q];
  }

  const u32x4* xf4 = (const u32x4*)xf;

  for (int st = 0; st < 4; ++st) {
    const size_t rg0 = (size_t)chunk * 64 + st * 16;
    const u32x4* gA = xf4 + (rg0 + w) * 512 + l;
    const u32x4* gB = xf4 + (rg0 + 8 + w) * 512 + l;

    f32x4 ak[2][4] = {{fz, fz, fz, fz}, {fz, fz, fz, fz}};
#pragma unroll
    for (int ks = 0; ks < 8; ++ks) {
      const bf16x8 xaA = *(const bf16x8*)(gA + ks * 64);
      const bf16x8 xaB = *(const bf16x8*)(gB + ks * 64);
#pragma unroll
      for (int jj = 0; jj < 4; ++jj) {
        const bf16x8 bwk = *(const bf16x8*)(lds + ((ks * 4 + jj) * 64 + l) * 16);
        ak[0][jj] = __builtin_amdgcn_mfma_f32_16x16x32_bf16(xaA, bwk, ak[0][jj], 0, 0, 0);
        ak[1][jj] = __builtin_amdgcn_mfma_f32_16x16x32_bf16(xaB, bwk, ak[1][jj], 0, 0, 0);
      }
    }
    bf16x8 pk[4];
#pragma unroll
    for (int jj = 0; jj < 4; ++jj) {
      float s = 0.f;
      bf16x8 p;
#pragma unroll
      for (int r = 0; r < 4; ++r) {
        const unsigned short u0 = f2bf(__expf(ak[0][jj][r] + bk[jj]));
        const unsigned short u1 = f2bf(__expf(ak[1][jj][r] + bk[jj]));
        p[r] = (short)u0; p[r + 4] = (short)u1;
        s += bf2f(u0) + bf2f(u1);
      }
      pk[jj] = p;
      srow[jj] += s;
    }

    asm volatile("" ::: "memory");   // block xa-fragment CSE across phases (spill guard)

    f32x4 av[2][4] = {{fz, fz, fz, fz}, {fz, fz, fz, fz}};
#pragma unroll
    for (int ks = 0; ks < 8; ++ks) {
      const bf16x8 xaA = *(const bf16x8*)(gA + ks * 64);
      const bf16x8 xaB = *(const bf16x8*)(gB + ks * 64);
#pragma unroll
      for (int jj = 0; jj < 4; ++jj) {
        const bf16x8 bwv = *(const bf16x8*)(lds + (((8 + ks) * 4 + jj) * 64 + l) * 16);
        av[0][jj] = __builtin_amdgcn_mfma_f32_16x16x32_bf16(xaA, bwv, av[0][jj], 0, 0, 0);
        av[1][jj] = __builtin_amdgcn_mfma_f32_16x16x32_bf16(xaB, bwv, av[1][jj], 0, 0, 0);
      }
    }
    bf16x8 pv[4];
#pragma unroll
    for (int jj = 0; jj < 4; ++jj) {
      bf16x8 p;
#pragma unroll
      for (int r = 0; r < 4; ++r) {
        p[r]     = (short)f2bf(av[0][jj][r] + bv[jj]);
        p[r + 4] = (short)f2bf(av[1][jj][r] + bv[jj]);
      }
      pv[jj] = p;
    }

#pragma unroll
    for (int ja = 0; ja < 4; ++ja)
#pragma unroll
      for (int jb = 0; jb < 4; ++jb)
        ctxa[ja][jb] = __builtin_amdgcn_mfma_f32_16x16x32_bf16(pk[ja], pv[jb], ctxa[ja][jb], 0, 0, 0);
  }

  __syncthreads();
  {
    float* srl = (float*)(lds + 65536);
#pragma unroll
    for (int jj = 0; jj < 4; ++jj) {
      float s = srow[jj];
      s += __shfl_xor(s, 16, 64);
      s += __shfl_xor(s, 32, 64);
      if (l < 16) srl[w * 64 + jj * 16 + q] = s;
    }
  }
  if (w < 4) {
    float* dw = (float*)lds + w * 4096 + l * 4;
#pragma unroll
    for (int ja = 0; ja < 4; ++ja)
#pragma unroll
      for (int jb = 0; jb < 4; ++jb)
        *(f32x4*)(dw + (ja * 4 + jb) * 256) = ctxa[ja][jb];
  }
  __syncthreads();
  f32x4 part0 = fz, part1 = fz;
  {
    const float* dump = (const float*)lds;
#pragma unroll
    for (int w4 = 0; w4 < 4; ++w4) {
      part0 += *(const f32x4*)(dump + w4 * 4096 + t * 4);
      part1 += *(const f32x4*)(dump + w4 * 4096 + (512 + t) * 4);
    }
  }
  __syncthreads();
  if (w >= 4) {
    float* dw = (float*)lds + (w - 4) * 4096 + l * 4;
#pragma unroll
    for (int ja = 0; ja < 4; ++ja)
#pragma unroll
      for (int jb = 0; jb < 4; ++jb)
        *(f32x4*)(dw + (ja * 4 + jb) * 256) = ctxa[ja][jb];
  }
  __syncthreads();
  {
    const float* dump = (const float*)lds;
#pragma unroll
    for (int w4 = 0; w4 < 4; ++w4) {
      part0 += *(const f32x4*)(dump + w4 * 4096 + t * 4);
      part1 += *(const f32x4*)(dump + w4 * 4096 + (512 + t) * 4);
    }
    float* cp = ctxp + (size_t)blockIdx.x * 4096;
    *(f32x4*)(cp + t * 4) = part0;
    *(f32x4*)(cp + (512 + t) * 4) = part1;
    if (t < 64) {
      const float* srl = (const float*)(lds + 65536);
      float s = 0.f;
#pragma unroll
      for (int w8 = 0; w8 < 8; ++w8) s += srl[w8 * 64 + t];
      sump[(size_t)(h * 64 + t) * 64 + chunk] = s;
    }
  }
}

// ---------------- W2 (absorbs ctxred+sexp): r-th block gathers its own ctx row ----------------
// ctxp float index within a (h,chunk) block: f(d,e) = (d>>4)*1024 + ((d>>2)&3)*64
//   + (d&3) + (e>>4)*256 + (e&15)*4   (inverse of k_kvctx's verified dump layout)
__global__ void k_w2(const float* __restrict__ ctxp, const float* __restrict__ sump,
                     const float* __restrict__ out_w, float* __restrict__ w2) {
  const int r = blockIdx.x;            // h*64+d
  const int h = r >> 6, d = r & 63;
  __shared__ float red[256];
  __shared__ float row[64];
  __shared__ float sinv;
  const int t = threadIdx.x;
  const int e = t & 63, cg = t >> 6;
  const int fe = (d >> 4) * 1024 + ((d >> 2) & 3) * 64 + (d & 3)
               + (e >> 4) * 256 + (e & 15) * 4;
  {
    const float* cp = ctxp + ((size_t)(h * 64 + cg * 16)) * 4096 + fe;
    float s = 0.f;
#pragma unroll
    for (int i = 0; i < 16; ++i) s += cp[(size_t)i * 4096];
    red[t] = s;
  }
  __syncthreads();
  if (t < 64) {
    row[t] = red[t] + red[64 + t] + red[128 + t] + red[192 + t];
    float sv = sump[(size_t)r * 64 + t];
    sv += __shfl_xor(sv, 1, 64);  sv += __shfl_xor(sv, 2, 64);
    sv += __shfl_xor(sv, 4, 64);  sv += __shfl_xor(sv, 8, 64);
    sv += __shfl_xor(sv, 16, 64); sv += __shfl_xor(sv, 32, 64);
    if (t == 0) sinv = 1.0f / sv;
  }
  __syncthreads();
  float a = 0.f;
  const float* wp = out_w + (size_t)t * 512 + h * 64;
#pragma unroll 8
  for (int e2 = 0; e2 < 64; ++e2) a += wp[e2] * row[e2];
  w2[(size_t)t * 512 + r] = a * sinv;
}

// ---------------- Weff = W2 @ Wq + beff + in-kernel a-scaled fragment pack ----------------
__global__ void k_weff(const float* __restrict__ w2, const float* __restrict__ qkv_w,
                       const float* __restrict__ bqv, const float* __restrict__ out_b,
                       const float* __restrict__ ab,
                       unsigned short* __restrict__ wef, float* __restrict__ beff) {
  const int o = blockIdx.x;
  const int c = threadIdx.x;
  __shared__ float rowv[512];
  __shared__ float red[256];
  __shared__ float wl[256];
  rowv[c] = w2[(size_t)o * 512 + c];
  rowv[256 + c] = w2[(size_t)o * 512 + 256 + c];
  __syncthreads();
  float a = 0.f;
#pragma unroll 8
  for (int r = 0; r < 512; ++r) a += rowv[r] * qkv_w[(size_t)r * 256 + c];
  wl[c] = a * ab[c];
  red[c] = rowv[c] * bqv[c] + rowv[256 + c] * bqv[256 + c];
  __syncthreads();
  for (int st = 128; st > 0; st >>= 1) {
    if (c < st) red[c] += red[c + st];
    __syncthreads();
  }
  if (c == 0) beff[o] = out_b[o] + red[0];
  // fragment pack: 32 chunks of 8 channels (row o of Weff, a-scaled)
  if (c < 32) {
    const int ks = c >> 2, lg = c & 3;
    const int cf = o >> 4, l = lg * 16 + (o & 15);
    union { unsigned short s[8]; u32x4 v; } u;
#pragma unroll
    for (int j = 0; j < 8; ++j) u.s[j] = f2bf(wl[ks * 32 + lg * 8 + j]);
    *(u32x4*)(wef + ((size_t)(ks * 16 + cf) * 64 + l) * 8) = u.v;
  }
}

// ---------------- final GEMM + coalesced epilogue ----------------
__launch_bounds__(256, 2)
__global__ void k_final(const unsigned short* __restrict__ xf,
                        const unsigned short* __restrict__ wef,
                        const float* __restrict__ beff,
                        float* __restrict__ out) {
  __shared__ unsigned short xlds[32768];
  const int t = threadIdx.x;
  const int w = t >> 6, l = t & 63;
  const int q = l & 15, g = l >> 4;
  const int si = w >> 1, sj = w & 1;
  const int bid = (blockIdx.x & 7) * 64 + (blockIdx.x >> 3);
  const size_t n0 = (size_t)bid * 128;
  {
    const u32x4* gs = (const u32x4*)xf + (size_t)bid * 4096;
    u32x4* ld = (u32x4*)xlds;
#pragma unroll
    for (int k2 = 0; k2 < 16; ++k2)
      ld[t + 256 * k2] = gs[t + 256 * k2];
  }
  __syncthreads();
  const f32x4 fz = {0.f, 0.f, 0.f, 0.f};
  f32x4 acc[4][8];
#pragma unroll
  for (int i = 0; i < 4; ++i)
#pragma unroll
    for (int j = 0; j < 8; ++j) acc[i][j] = fz;
#pragma unroll
  for (int ks = 0; ks < 8; ++ks) {
    bf16x8 xa[4];
#pragma unroll
    for (int i = 0; i < 4; ++i)
      xa[i] = *(const bf16x8*)((const char*)xlds + (((si * 4 + i) * 8 + ks) * 64 + l) * 16);
#pragma unroll
    for (int jj = 0; jj < 8; ++jj) {
      const bf16x8 bw = *(const bf16x8*)(wef + (((size_t)(ks * 16 + sj * 8 + jj)) * 64 + l) * 8);
#pragma unroll
      for (int i = 0; i < 4; ++i)
        acc[i][jj] = __builtin_amdgcn_mfma_f32_16x16x32_bf16(xa[i], bw, acc[i][jj], 0, 0, 0);
    }
  }
  __syncthreads();
  float* trf = (float*)xlds;
#pragma unroll
  for (int k4 = 0; k4 < 4; ++k4) {
    if ((k4 >> 1) == sj) {
#pragma unroll
      for (int jj2 = 0; jj2 < 4; ++jj2) {
        const int jj = (k4 & 1) * 4 + jj2;
        const float be = beff[sj * 128 + jj * 16 + q];
#pragma unroll
        for (int i = 0; i < 4; ++i)
#pragma unroll
          for (int r = 0; r < 4; ++r)
            trf[(jj2 * 16 + q) * 129 + si * 64 + i * 16 + g * 4 + r] = acc[i][jj][r] + be;
      }
    }
    __syncthreads();
#pragma unroll
    for (int j = 0; j < 32; ++j) {
      const int mm = j * 256 + t;
      const int ol = mm >> 7, cc = mm & 127;
      out[(size_t)(k4 * 64 + ol) * NSP + n0 + cc] = trf[ol * 129 + cc];
    }
    __syncthreads();
  }
}

extern "C" void kernel_launch(void* const* d_in, const int* in_sizes, int n_in,
                              void* d_out, int out_size, void* d_ws, size_t ws_size,
                              hipStream_t stream) {
  const float* x     = (const float*)d_in[0];
  const float* gn_w  = (const float*)d_in[1];
  const float* gn_b  = (const float*)d_in[2];
  const float* qkv_w = (const float*)d_in[3];
  const float* qkv_b = (const float*)d_in[4];
  const float* out_w = (const float*)d_in[5];
  const float* out_b = (const float*)d_in[6];
  char* ws = (char*)d_ws;
  unsigned short* xf  = (unsigned short*)(ws + WS_XN);
  unsigned short* wf  = (unsigned short*)(ws + WS_WFRAG);
  unsigned short* wef = (unsigned short*)(ws + WS_WEFRAG);
  float* ab     = (float*)(ws + WS_AB);
  float* w2     = (float*)(ws + WS_W2);
  float* beff   = (float*)(ws + WS_BEFF);
  float* bqv    = (float*)(ws + WS_BQV);
  float* out    = (float*)d_out;
  // d_out scratch (all consumed before k_final writes out):
  float* ctxp = (float*)((char*)d_out + 33554432ULL);       //  8 MB
  float* sump = (float*)((char*)d_out + 41943040ULL);       // 128 KB
  float* p2s  = (float*)((char*)d_out + 46137344ULL);       //  1 MB
  float* p2q  = (float*)((char*)d_out + 47185920ULL);       //  1 MB

  k_xnstats<<<dim3(1024, 4), 256, 0, stream>>>(x, xf, p2s, p2q);
  k_coefg<<<32, 256, 0, stream>>>(p2s, p2q, gn_w, gn_b, ab);
  k_wfrag<<<512, 64, 0, stream>>>(qkv_w, ab, wf);
  k_bkv<<<384, 64, 0, stream>>>(qkv_w, qkv_b, ab, bqv);
  k_kvctx<<<512, 512, 0, stream>>>(xf, wf, bqv, sump, ctxp);
  k_w2<<<512, 256, 0, stream>>>(ctxp, sump, out_w, w2);
  k_weff<<<256, 256, 0, stream>>>(w2, qkv_w, bqv, out_b, ab, wef, beff);
  k_final<<<512, 256, 0, stream>>>(xf, wef, beff, out);
}

// Round 23
// 169.949 us; speedup vs baseline: 1.0208x; 1.0025x over previous
//
#include <hip/hip_runtime.h>
#include <stdint.h>

typedef __attribute__((ext_vector_type(8))) short bf16x8;
typedef __attribute__((ext_vector_type(4))) float f32x4;
typedef __attribute__((ext_vector_type(4))) unsigned int u32x4;

#define NSP 65536

// workspace byte offsets
#define WS_XN     0ULL         // 33554432  bf16 xf = bf16(x) fragment-native
#define WS_WFRAG  33554432ULL  // 524288    a-scaled Wkv fragment buffer
#define WS_WEFRAG 34078720ULL  // 131072    a-scaled Weff fragment buffer
#define WS_AB     34211840ULL  // 2048      per-channel a,b
#define WS_W2     34347008ULL  // 1048576   W2[256][512]
#define WS_BEFF   35657728ULL  // 1024      beff[256]
#define WS_BQV    35658752ULL  // 6144      b-folded qkv biases [1536]

// d_out scratch (consumed before k_final overwrites d_out):
//   ctxp (f32) [32MB..40MB)   512 blocks * 4096 partials
//   sump (f32) [40MB..+128KB) [h*64+d][chunk64]
//   p2s  (f32) [44MB..+1MB)   per-channel partial sums [256][1024]
//   p2q  (f32) [45MB..+1MB)   per-channel partial sumsq

__device__ __forceinline__ unsigned short f2bf(float f) {
  union { float f; uint32_t u; } v; v.f = f;
  uint32_t r = v.u + 0x7FFFu + ((v.u >> 16) & 1u);
  return (unsigned short)(r >> 16);
}
__device__ __forceinline__ float bf2f(unsigned short b) {
  union { uint32_t u; float f; } v; v.u = ((uint32_t)b) << 16;
  return v.f;
}

// ---------------- fused: cast+transpose to fragments + per-channel stats ----------------
__global__ void k_xnstats(const float* __restrict__ x, unsigned short* __restrict__ xf,
                          float* __restrict__ p2s, float* __restrict__ p2q) {
  __shared__ float tile[64][66];
  const int t = threadIdx.x;
  const int nb = blockIdx.x, cb = blockIdx.y;
  {
    const int cl = t >> 2, nc = t & 3;
    const int c = cb * 64 + cl;
    const f32x4* src = (const f32x4*)(x + (size_t)c * NSP + nb * 64 + nc * 16);
    float s = 0.f, qq = 0.f;
#pragma unroll
    for (int j = 0; j < 4; ++j) {
      f32x4 v = __builtin_nontemporal_load(src + j);
      *(f32x4*)&tile[cl][nc * 16 + j * 4] = v;
      s  += v[0] + v[1] + v[2] + v[3];
      qq += v[0] * v[0] + v[1] * v[1] + v[2] * v[2] + v[3] * v[3];
    }
    s  += __shfl_xor(s, 1, 64);  s  += __shfl_xor(s, 2, 64);
    qq += __shfl_xor(qq, 1, 64); qq += __shfl_xor(qq, 2, 64);
    if (nc == 0) {
      p2s[(size_t)(cb * 64 + cl) * 1024 + nb] = s;
      p2q[(size_t)(cb * 64 + cl) * 1024 + nb] = qq;
    }
  }
  __syncthreads();
  {
    const int l = t & 63, w0 = t >> 6;
    u32x4* xf4 = (u32x4*)xf;
#pragma unroll
    for (int u2 = 0; u2 < 2; ++u2) {
      const int fp = w0 + u2 * 4;
      const int fl = fp >> 1, ksl = fp & 1;
      union { unsigned short s[8]; u32x4 v; } pk2;
#pragma unroll
      for (int e = 0; e < 8; ++e)
        pk2.s[e] = f2bf(tile[ksl * 32 + (l >> 4) * 8 + e][fl * 16 + (l & 15)]);
      xf4[((size_t)(nb * 4 + fl) * 8 + cb * 2 + ksl) * 64 + l] = pk2.v;
    }
  }
}

// ---------------- group stats -> per-channel a,b ----------------
__global__ void k_coefg(const float* __restrict__ p2s, const float* __restrict__ p2q,
                        const float* __restrict__ gn_w, const float* __restrict__ gn_b,
                        float* __restrict__ ab) {
  __shared__ float rs[256], rq[256];
  const int g = blockIdx.x, t = threadIdx.x;
  const float* ps = p2s + (size_t)g * 8192;
  const float* pq = p2q + (size_t)g * 8192;
  float s = 0.f, q = 0.f;
  for (int i = t; i < 8192; i += 256) { s += ps[i]; q += pq[i]; }
  rs[t] = s; rq[t] = q;
  __syncthreads();
  for (int st = 128; st > 0; st >>= 1) {
    if (t < st) { rs[t] += rs[t + st]; rq[t] += rq[t + st]; }
    __syncthreads();
  }
  if (t < 8) {
    const int c = g * 8 + t;
    const float inv = 1.0f / 524288.0f;
    const float mean = rs[0] * inv;
    const float var = rq[0] * inv - mean * mean;
    const float rstd = rsqrtf(var + 1e-5f);
    const float a = gn_w[c] * rstd;
    ab[c] = a;
    ab[256 + c] = gn_b[c] - mean * a;
  }
}

// ---------------- a-scaled Wkv rows -> MFMA B-fragment order ----------------
__global__ void k_wfrag(const float* __restrict__ qkv_w, const float* __restrict__ ab,
                        unsigned short* __restrict__ wf) {
  const int blk = blockIdx.x;
  const int l = threadIdx.x;
  const int row = 512 + (blk & 63) * 16 + (l & 15);
  const int c0 = (blk >> 6) * 32 + (l >> 4) * 8;
  const float* src = qkv_w + (size_t)row * 256 + c0;
  union { unsigned short s[8]; u32x4 v; } u;
#pragma unroll
  for (int j = 0; j < 8; ++j) u.s[j] = f2bf(src[j] * ab[c0 + j]);
  *(u32x4*)(wf + ((size_t)blk * 64 + l) * 8) = u.v;
}

// ---------------- b-folded biases ----------------
__global__ void k_bkv(const float* __restrict__ qkv_w, const float* __restrict__ qkv_b,
                      const float* __restrict__ ab, float* __restrict__ bqv) {
  const int l = threadIdx.x;
  const int r = blockIdx.x * 4 + (l >> 4);
  const int li = l & 15;
  const float* wr = qkv_w + (size_t)r * 256 + li * 16;
  float s = 0.f;
#pragma unroll
  for (int j = 0; j < 16; ++j) s += wr[j] * ab[256 + li * 16 + j];
  s += __shfl_xor(s, 1, 64);
  s += __shfl_xor(s, 2, 64);
  s += __shfl_xor(s, 4, 64);
  s += __shfl_xor(s, 8, 64);
  if (li == 0) bqv[r] = qkv_b[r] + s;
}

// ---------------- fused KV-GEMM + exp + in-register context (frozen @63us) ----------------
__launch_bounds__(512, 1)
__global__ void k_kvctx(const unsigned short* __restrict__ xf,
                        const unsigned short* __restrict__ wfrag,
                        const float* __restrict__ bqv,
                        float* __restrict__ sump, float* __restrict__ ctxp) {
  __shared__ __align__(16) char lds[67584];
  const int t = threadIdx.x;
  const int w = t >> 6, l = t & 63;
  const int q = l & 15;
  const int h = blockIdx.x >> 6;
  const int chunk = blockIdx.x & 63;

  {
    const u32x4* wsrc = (const u32x4*)wfrag;
    u32x4* wdst = (u32x4*)lds;
#pragma unroll
    for (int r = 0; r < 8; ++r) {
      const int e = r * 512 + t;
      const int entry = e >> 6, l2 = e & 63;
      const int ph = entry >> 5, ks = (entry >> 2) & 7, jj = entry & 3;
      wdst[e] = wsrc[((size_t)(ks * 64 + ph * 32 + h * 4 + jj)) * 64 + l2];
    }
  }
  __syncthreads();

  const f32x4 fz = {0.f, 0.f, 0.f, 0.f};
  f32x4 ctxa[4][4];
#pragma unroll
  for (int a = 0; a < 4; ++a)
#pragma unroll
    for (int b = 0; b < 4; ++b) ctxa[a][b] = fz;
  float srow[4] = {0.f, 0.f, 0.f, 0.f};
  float bk[4], bv[4];
#pragma unroll
  for (int jj = 0; jj < 4; ++jj) {
    bk[jj] = bqv[512 + h * 64 + jj * 16 + q];
    bv[jj] = bqv[1024 + h * 64 + jj * 16 + q];
  }

  const u32x4* xf4 = (const u32x4*)xf;

  for (int st = 0; st < 4; ++st) {
    const size_t rg0 = (size_t)chunk * 64 + st * 16;
    const u32x4* gA = xf4 + (rg0 + w) * 512 + l;
    const u32x4* gB = xf4 + (rg0 + 8 + w) * 512 + l;

    f32x4 ak[2][4] = {{fz, fz, fz, fz}, {fz, fz, fz, fz}};
#pragma unroll
    for (int ks = 0; ks < 8; ++ks) {
      const bf16x8 xaA = *(const bf16x8*)(gA + ks * 64);
      const bf16x8 xaB = *(const bf16x8*)(gB + ks * 64);
#pragma unroll
      for (int jj = 0; jj < 4; ++jj) {
        const bf16x8 bwk = *(const bf16x8*)(lds + ((ks * 4 + jj) * 64 + l) * 16);
        ak[0][jj] = __builtin_amdgcn_mfma_f32_16x16x32_bf16(xaA, bwk, ak[0][jj], 0, 0, 0);
        ak[1][jj] = __builtin_amdgcn_mfma_f32_16x16x32_bf16(xaB, bwk, ak[1][jj], 0, 0, 0);
      }
    }
    bf16x8 pk[4];
#pragma unroll
    for (int jj = 0; jj < 4; ++jj) {
      float s = 0.f;
      bf16x8 p;
#pragma unroll
      for (int r = 0; r < 4; ++r) {
        const unsigned short u0 = f2bf(__expf(ak[0][jj][r] + bk[jj]));
        const unsigned short u1 = f2bf(__expf(ak[1][jj][r] + bk[jj]));
        p[r] = (short)u0; p[r + 4] = (short)u1;
        s += bf2f(u0) + bf2f(u1);
      }
      pk[jj] = p;
      srow[jj] += s;
    }

    asm volatile("" ::: "memory");   // block xa-fragment CSE across phases (spill guard)

    f32x4 av[2][4] = {{fz, fz, fz, fz}, {fz, fz, fz, fz}};
#pragma unroll
    for (int ks = 0; ks < 8; ++ks) {
      const bf16x8 xaA = *(const bf16x8*)(gA + ks * 64);
      const bf16x8 xaB = *(const bf16x8*)(gB + ks * 64);
#pragma unroll
      for (int jj = 0; jj < 4; ++jj) {
        const bf16x8 bwv = *(const bf16x8*)(lds + (((8 + ks) * 4 + jj) * 64 + l) * 16);
        av[0][jj] = __builtin_amdgcn_mfma_f32_16x16x32_bf16(xaA, bwv, av[0][jj], 0, 0, 0);
        av[1][jj] = __builtin_amdgcn_mfma_f32_16x16x32_bf16(xaB, bwv, av[1][jj], 0, 0, 0);
      }
    }
    bf16x8 pv[4];
#pragma unroll
    for (int jj = 0; jj < 4; ++jj) {
      bf16x8 p;
#pragma unroll
      for (int r = 0; r < 4; ++r) {
        p[r]     = (short)f2bf(av[0][jj][r] + bv[jj]);
        p[r + 4] = (short)f2bf(av[1][jj][r] + bv[jj]);
      }
      pv[jj] = p;
    }

#pragma unroll
    for (int ja = 0; ja < 4; ++ja)
#pragma unroll
      for (int jb = 0; jb < 4; ++jb)
        ctxa[ja][jb] = __builtin_amdgcn_mfma_f32_16x16x32_bf16(pk[ja], pv[jb], ctxa[ja][jb], 0, 0, 0);
  }

  __syncthreads();
  {
    float* srl = (float*)(lds + 65536);
#pragma unroll
    for (int jj = 0; jj < 4; ++jj) {
      float s = srow[jj];
      s += __shfl_xor(s, 16, 64);
      s += __shfl_xor(s, 32, 64);
      if (l < 16) srl[w * 64 + jj * 16 + q] = s;
    }
  }
  if (w < 4) {
    float* dw = (float*)lds + w * 4096 + l * 4;
#pragma unroll
    for (int ja = 0; ja < 4; ++ja)
#pragma unroll
      for (int jb = 0; jb < 4; ++jb)
        *(f32x4*)(dw + (ja * 4 + jb) * 256) = ctxa[ja][jb];
  }
  __syncthreads();
  f32x4 part0 = fz, part1 = fz;
  {
    const float* dump = (const float*)lds;
#pragma unroll
    for (int w4 = 0; w4 < 4; ++w4) {
      part0 += *(const f32x4*)(dump + w4 * 4096 + t * 4);
      part1 += *(const f32x4*)(dump + w4 * 4096 + (512 + t) * 4);
    }
  }
  __syncthreads();
  if (w >= 4) {
    float* dw = (float*)lds + (w - 4) * 4096 + l * 4;
#pragma unroll
    for (int ja = 0; ja < 4; ++ja)
#pragma unroll
      for (int jb = 0; jb < 4; ++jb)
        *(f32x4*)(dw + (ja * 4 + jb) * 256) = ctxa[ja][jb];
  }
  __syncthreads();
  {
    const float* dump = (const float*)lds;
#pragma unroll
    for (int w4 = 0; w4 < 4; ++w4) {
      part0 += *(const f32x4*)(dump + w4 * 4096 + t * 4);
      part1 += *(const f32x4*)(dump + w4 * 4096 + (512 + t) * 4);
    }
    float* cp = ctxp + (size_t)blockIdx.x * 4096;
    *(f32x4*)(cp + t * 4) = part0;
    *(f32x4*)(cp + (512 + t) * 4) = part1;
    if (t < 64) {
      const float* srl = (const float*)(lds + 65536);
      float s = 0.f;
#pragma unroll
      for (int w8 = 0; w8 < 8; ++w8) s += srl[w8 * 64 + t];
      sump[(size_t)(h * 64 + t) * 64 + chunk] = s;
    }
  }
}

// ---------------- W2 (absorbs ctxred+sexp): r-th block gathers its own ctx row ----------------
// ctxp float index within a (h,chunk) block: f(d,e) = (d>>4)*1024 + ((d>>2)&3)*64
//   + (d&3) + (e>>4)*256 + (e&15)*4   (inverse of k_kvctx's verified dump layout)
__global__ void k_w2(const float* __restrict__ ctxp, const float* __restrict__ sump,
                     const float* __restrict__ out_w, float* __restrict__ w2) {
  const int r = blockIdx.x;            // h*64+d
  const int h = r >> 6, d = r & 63;
  __shared__ float red[256];
  __shared__ float row[64];
  __shared__ float sinv;
  const int t = threadIdx.x;
  const int e = t & 63, cg = t >> 6;
  const int fe = (d >> 4) * 1024 + ((d >> 2) & 3) * 64 + (d & 3)
               + (e >> 4) * 256 + (e & 15) * 4;
  {
    const float* cp = ctxp + ((size_t)(h * 64 + cg * 16)) * 4096 + fe;
    float s = 0.f;
#pragma unroll
    for (int i = 0; i < 16; ++i) s += cp[(size_t)i * 4096];
    red[t] = s;
  }
  __syncthreads();
  if (t < 64) {
    row[t] = red[t] + red[64 + t] + red[128 + t] + red[192 + t];
    float sv = sump[(size_t)r * 64 + t];
    sv += __shfl_xor(sv, 1, 64);  sv += __shfl_xor(sv, 2, 64);
    sv += __shfl_xor(sv, 4, 64);  sv += __shfl_xor(sv, 8, 64);
    sv += __shfl_xor(sv, 16, 64); sv += __shfl_xor(sv, 32, 64);
    if (t == 0) sinv = 1.0f / sv;
  }
  __syncthreads();
  float a = 0.f;
  const float* wp = out_w + (size_t)t * 512 + h * 64;
#pragma unroll 8
  for (int e2 = 0; e2 < 64; ++e2) a += wp[e2] * row[e2];
  w2[(size_t)t * 512 + r] = a * sinv;
}

// ---------------- Weff = W2 @ Wq + beff + in-kernel a-scaled fragment pack ----------------
__global__ void k_weff(const float* __restrict__ w2, const float* __restrict__ qkv_w,
                       const float* __restrict__ bqv, const float* __restrict__ out_b,
                       const float* __restrict__ ab,
                       unsigned short* __restrict__ wef, float* __restrict__ beff) {
  const int o = blockIdx.x;
  const int c = threadIdx.x;
  __shared__ float rowv[512];
  __shared__ float red[256];
  __shared__ float wl[256];
  rowv[c] = w2[(size_t)o * 512 + c];
  rowv[256 + c] = w2[(size_t)o * 512 + 256 + c];
  __syncthreads();
  float a = 0.f;
#pragma unroll 8
  for (int r = 0; r < 512; ++r) a += rowv[r] * qkv_w[(size_t)r * 256 + c];
  wl[c] = a * ab[c];
  red[c] = rowv[c] * bqv[c] + rowv[256 + c] * bqv[256 + c];
  __syncthreads();
  for (int st = 128; st > 0; st >>= 1) {
    if (c < st) red[c] += red[c + st];
    __syncthreads();
  }
  if (c == 0) beff[o] = out_b[o] + red[0];
  // fragment pack: 32 chunks of 8 channels (row o of Weff, a-scaled)
  if (c < 32) {
    const int ks = c >> 2, lg = c & 3;
    const int cf = o >> 4, l = lg * 16 + (o & 15);
    union { unsigned short s[8]; u32x4 v; } u;
#pragma unroll
    for (int j = 0; j < 8; ++j) u.s[j] = f2bf(wl[ks * 32 + lg * 8 + j]);
    *(u32x4*)(wef + ((size_t)(ks * 16 + cf) * 64 + l) * 8) = u.v;
  }
}

// ---------------- final GEMM + coalesced epilogue ----------------
__launch_bounds__(256, 2)
__global__ void k_final(const unsigned short* __restrict__ xf,
                        const unsigned short* __restrict__ wef,
                        const float* __restrict__ beff,
                        float* __restrict__ out) {
  __shared__ unsigned short xlds[32768];
  const int t = threadIdx.x;
  const int w = t >> 6, l = t & 63;
  const int q = l & 15, g = l >> 4;
  const int si = w >> 1, sj = w & 1;
  const int bid = (blockIdx.x & 7) * 64 + (blockIdx.x >> 3);
  const size_t n0 = (size_t)bid * 128;
  {
    const u32x4* gs = (const u32x4*)xf + (size_t)bid * 4096;
    u32x4* ld = (u32x4*)xlds;
#pragma unroll
    for (int k2 = 0; k2 < 16; ++k2)
      ld[t + 256 * k2] = gs[t + 256 * k2];
  }
  __syncthreads();
  const f32x4 fz = {0.f, 0.f, 0.f, 0.f};
  f32x4 acc[4][8];
#pragma unroll
  for (int i = 0; i < 4; ++i)
#pragma unroll
    for (int j = 0; j < 8; ++j) acc[i][j] = fz;
#pragma unroll
  for (int ks = 0; ks < 8; ++ks) {
    bf16x8 xa[4];
#pragma unroll
    for (int i = 0; i < 4; ++i)
      xa[i] = *(const bf16x8*)((const char*)xlds + (((si * 4 + i) * 8 + ks) * 64 + l) * 16);
#pragma unroll
    for (int jj = 0; jj < 8; ++jj) {
      const bf16x8 bw = *(const bf16x8*)(wef + (((size_t)(ks * 16 + sj * 8 + jj)) * 64 + l) * 8);
#pragma unroll
      for (int i = 0; i < 4; ++i)
        acc[i][jj] = __builtin_amdgcn_mfma_f32_16x16x32_bf16(xa[i], bw, acc[i][jj], 0, 0, 0);
    }
  }
  __syncthreads();
  float* trf = (float*)xlds;
#pragma unroll
  for (int k4 = 0; k4 < 4; ++k4) {
    if ((k4 >> 1) == sj) {
#pragma unroll
      for (int jj2 = 0; jj2 < 4; ++jj2) {
        const int jj = (k4 & 1) * 4 + jj2;
        const float be = beff[sj * 128 + jj * 16 + q];
#pragma unroll
        for (int i = 0; i < 4; ++i)
#pragma unroll
          for (int r = 0; r < 4; ++r)
            trf[(jj2 * 16 + q) * 129 + si * 64 + i * 16 + g * 4 + r] = acc[i][jj][r] + be;
      }
    }
    __syncthreads();
#pragma unroll
    for (int j = 0; j < 32; ++j) {
      const int mm = j * 256 + t;
      const int ol = mm >> 7, cc = mm & 127;
      out[(size_t)(k4 * 64 + ol) * NSP + n0 + cc] = trf[ol * 129 + cc];
    }
    __syncthreads();
  }
}

extern "C" void kernel_launch(void* const* d_in, const int* in_sizes, int n_in,
                              void* d_out, int out_size, void* d_ws, size_t ws_size,
                              hipStream_t stream) {
  const float* x     = (const float*)d_in[0];
  const float* gn_w  = (const float*)d_in[1];
  const float* gn_b  = (const float*)d_in[2];
  const float* qkv_w = (const float*)d_in[3];
  const float* qkv_b = (const float*)d_in[4];
  const float* out_w = (const float*)d_in[5];
  const float* out_b = (const float*)d_in[6];
  char* ws = (char*)d_ws;
  unsigned short* xf  = (unsigned short*)(ws + WS_XN);
  unsigned short* wf  = (unsigned short*)(ws + WS_WFRAG);
  unsigned short* wef = (unsigned short*)(ws + WS_WEFRAG);
  float* ab     = (float*)(ws + WS_AB);
  float* w2     = (float*)(ws + WS_W2);
  float* beff   = (float*)(ws + WS_BEFF);
  float* bqv    = (float*)(ws + WS_BQV);
  float* out    = (float*)d_out;
  // d_out scratch (all consumed before k_final writes out):
  float* ctxp = (float*)((char*)d_out + 33554432ULL);       //  8 MB
  float* sump = (float*)((char*)d_out + 41943040ULL);       // 128 KB
  float* p2s  = (float*)((char*)d_out + 46137344ULL);       //  1 MB
  float* p2q  = (float*)((char*)d_out + 47185920ULL);       //  1 MB

  k_xnstats<<<dim3(1024, 4), 256, 0, stream>>>(x, xf, p2s, p2q);
  k_coefg<<<32, 256, 0, stream>>>(p2s, p2q, gn_w, gn_b, ab);
  k_wfrag<<<512, 64, 0, stream>>>(qkv_w, ab, wf);
  k_bkv<<<384, 64, 0, stream>>>(qkv_w, qkv_b, ab, bqv);
  k_kvctx<<<512, 512, 0, stream>>>(xf, wf, bqv, sump, ctxp);
  k_w2<<<512, 256, 0, stream>>>(ctxp, sump, out_w, w2);
  k_weff<<<256, 256, 0, stream>>>(w2, qkv_w, bqv, out_b, ab, wef, beff);
  k_final<<<512, 256, 0, stream>>>(xf, wef, beff, out);
}